// Round 4
// baseline (87.243 us; speedup 1.0000x reference)
//
#include <hip/hip_runtime.h>

#define B_ 256
#define K_ 512
#define D_ 64
#define KD_ 576
#define LOG2E 1.44269504088896340736f

typedef float v4f __attribute__((ext_vector_type(4)));
typedef short bf16x8 __attribute__((ext_vector_type(8)));
typedef float f32x16 __attribute__((ext_vector_type(16)));

#define ZERO16 {0.f,0.f,0.f,0.f,0.f,0.f,0.f,0.f,0.f,0.f,0.f,0.f,0.f,0.f,0.f,0.f}

__device__ __forceinline__ float fexp2(float x) {
#if __has_builtin(__builtin_amdgcn_exp2f)
    return __builtin_amdgcn_exp2f(x);
#else
    float r; asm("v_exp_f32 %0, %1" : "=v"(r) : "v"(x)); return r;
#endif
}
__device__ __forceinline__ float frcp(float x) {
#if __has_builtin(__builtin_amdgcn_rcpf)
    return __builtin_amdgcn_rcpf(x);
#else
    float r; asm("v_rcp_f32 %0, %1" : "=v"(r) : "v"(x)); return r;
#endif
}
__device__ __forceinline__ float fsig(float x) {
    return frcp(1.0f + fexp2(-LOG2E * x));
}
__device__ __forceinline__ ushort f2bf(float f) {
    union { float f; unsigned u; } v; v.f = f;
    return (ushort)((v.u + 0x7FFFu + ((v.u >> 16) & 1u)) >> 16);
}
__device__ __forceinline__ bf16x8 ldcvt8(const float* p) {
    float4 a = *(const float4*)p;
    float4 b = *(const float4*)(p + 4);
    bf16x8 r;
    r[0] = (short)f2bf(a.x); r[1] = (short)f2bf(a.y);
    r[2] = (short)f2bf(a.z); r[3] = (short)f2bf(a.w);
    r[4] = (short)f2bf(b.x); r[5] = (short)f2bf(b.y);
    r[6] = (short)f2bf(b.z); r[7] = (short)f2bf(b.w);
    return r;
}

// ---------------------------------------------------------------------------
// kPrep (192 blocks x 256 thr):
//  [0,64):   Sb[tab][b][n] = bf16(sigmoid(table_row[b] . kn[n]))   MFMA, D=64
//  [64,192): F[mat][k][n]  = exp(-(kn[k] . W[n, K:K+D]))  f32      MFMA, D=64
//  block 0 also zeroes the 64 finisher counters.
// ---------------------------------------------------------------------------
__global__ void __launch_bounds__(256) kPrep(const int* __restrict__ sid,
                                             const int* __restrict__ eid,
                                             const float* __restrict__ stu_t,
                                             const float* __restrict__ exer_t,
                                             const float* __restrict__ kn_t,
                                             const float* __restrict__ W1,
                                             const float* __restrict__ W2,
                                             ushort* __restrict__ Sbu,
                                             float* __restrict__ F1,
                                             float* __restrict__ F2,
                                             unsigned* __restrict__ cnt) {
    const int bid = blockIdx.x, t = threadIdx.x;
    const int l = t & 63, w = t >> 6;
    const int dk = (l >> 5) * 8;
    if (bid == 0 && t < 64) cnt[t] = 0u;
    if (bid < 64) {
        const int tab = bid >> 5, bt = (bid >> 3) & 3, nt = bid & 7;
        const int b0 = bt * 64, n0 = nt * 64;
        const int brow = b0 + (w & 1) * 32 + (l & 31);
        const int ncol = n0 + (w >> 1) * 32 + (l & 31);
        const int id = (tab ? eid : sid)[brow];
        const float* ar = (tab ? exer_t : stu_t) + (size_t)id * D_;
        const float* br = kn_t + (size_t)ncol * D_;
        f32x16 acc = ZERO16;
#pragma unroll
        for (int kk = 0; kk < 4; kk++) {
            bf16x8 a = ldcvt8(ar + kk * 16 + dk);
            bf16x8 b = ldcvt8(br + kk * 16 + dk);
            acc = __builtin_amdgcn_mfma_f32_32x32x16_bf16(a, b, acc, 0, 0, 0);
        }
        ushort* So = Sbu + (size_t)tab * B_ * K_;
#pragma unroll
        for (int r = 0; r < 16; r++) {
            const int row = (r & 3) + 8 * (r >> 2) + 4 * (l >> 5);
            So[(size_t)(b0 + (w & 1) * 32 + row) * K_ + ncol] = f2bf(fsig(acc[r]));
        }
    } else {
        const int fid = bid - 64;
        const int mat = fid >> 6, kt = (fid >> 3) & 7, nt = fid & 7;
        const int k0 = kt * 64, n0 = nt * 64;
        const int krow = k0 + (w & 1) * 32 + (l & 31);
        const int ncol = n0 + (w >> 1) * 32 + (l & 31);
        const float* Wm = mat ? W2 : W1;
        const float* ar = kn_t + (size_t)krow * D_;
        const float* br = Wm + (size_t)ncol * KD_ + K_;
        f32x16 acc = ZERO16;
#pragma unroll
        for (int kk = 0; kk < 4; kk++) {
            bf16x8 a = ldcvt8(ar + kk * 16 + dk);
            bf16x8 b = ldcvt8(br + kk * 16 + dk);
            acc = __builtin_amdgcn_mfma_f32_32x32x16_bf16(a, b, acc, 0, 0, 0);
        }
        float* Fo = mat ? F2 : F1;
#pragma unroll
        for (int r = 0; r < 16; r++) {
            const int row = (r & 3) + 8 * (r >> 2) + 4 * (l >> 5);
            Fo[(size_t)(k0 + (w & 1) * 32 + row) * K_ + ncol] = fexp2(-LOG2E * acc[r]);
        }
    }
}

// ---------------------------------------------------------------------------
// kE (128 blocks x 256 thr): E[mat][b][n] = exp(-(S[b,:] . W[n,0:K]))
// Full K=512 contraction per block: out tile 32b x 64n; 4 waves =
// (n-quad 2) x (k-half 2); halves combined through LDS; exp fused on store.
// ---------------------------------------------------------------------------
__global__ void __launch_bounds__(256) kE(const ushort* __restrict__ Sbu,
                                          const float* __restrict__ W1,
                                          const float* __restrict__ W2,
                                          float* __restrict__ E) {
    __shared__ float lacc[4][32][33];
    const int bid = blockIdx.x, t = threadIdx.x;
    const int nt = bid & 7, bt = (bid >> 3) & 7, mat = bid >> 6;
    const int l = t & 63, w = t >> 6;
    const int q = w & 1, h = w >> 1;
    const int m0 = nt * 64, b0 = bt * 32;
    const int arow = b0 + (l & 31);
    const int brow = m0 + q * 32 + (l & 31);
    const float* W = mat ? W2 : W1;
    const short* Sp = (const short*)Sbu + (size_t)(mat * B_ + arow) * K_
                      + h * 256 + (l >> 5) * 8;
    const float* Wp = W + (size_t)brow * KD_ + h * 256 + (l >> 5) * 8;
    f32x16 acc = ZERO16;
#pragma unroll
    for (int kk = 0; kk < 16; kk++) {
        bf16x8 a = *(const bf16x8*)(Sp + kk * 16);
        bf16x8 b = ldcvt8(Wp + kk * 16);
        acc = __builtin_amdgcn_mfma_f32_32x32x16_bf16(a, b, acc, 0, 0, 0);
    }
#pragma unroll
    for (int r = 0; r < 16; r++) {
        const int row = (r & 3) + 8 * (r >> 2) + 4 * (l >> 5);
        lacc[h * 2 + q][row][l & 31] = acc[r];
    }
    __syncthreads();
#pragma unroll
    for (int i = 0; i < 8; i++) {
        const int o = t + i * 256;
        const int q2 = o >> 10, row = (o >> 5) & 31, col = o & 31;
        const float v = lacc[q2][row][col] + lacc[2 + q2][row][col];
        E[(size_t)mat * B_ * K_ + (size_t)(b0 + row) * K_ + m0 + q2 * 32 + col]
            = fexp2(-LOG2E * v);
    }
}

// ---------------------------------------------------------------------------
// kMain: grid (8 kg, 64 bg), 256 thr (4 waves). Lane owns n-slice [8l, 8l+8);
// e1/e2/w3 in regs; F rows per-lane from L2 (reg double-buffer); 32 (k,b)
// accumulators reduced across 64 lanes by recursive-halving butterfly.
// Fused deterministic finisher.
// ---------------------------------------------------------------------------
__global__ void __launch_bounds__(256) kMain(const float* __restrict__ F1,
                                             const float* __restrict__ F2,
                                             const float* __restrict__ Ebase,
                                             const float* __restrict__ W3,
                                             const float* __restrict__ b3,
                                             const float* __restrict__ kn_emb,
                                             float* __restrict__ partial,
                                             unsigned* __restrict__ cnt,
                                             float* __restrict__ out) {
    __shared__ float red[4][32];
    __shared__ int sdone;
    const int t = threadIdx.x;
    const int l = t & 63, w = t >> 6;
    const int kbase = blockIdx.x * 64;
    const int b0 = blockIdx.y * 4;
    const int kw = kbase + w * 16;
    const int n0 = l * 8;
    const float* E1 = Ebase;
    const float* E2 = Ebase + (size_t)B_ * K_;

    v4f e1v[4][2], e2v[4][2], w3v[2];
#pragma unroll
    for (int bi = 0; bi < 4; bi++)
#pragma unroll
        for (int c = 0; c < 2; c++) {
            e1v[bi][c] = *(const v4f*)(E1 + (size_t)(b0 + bi) * K_ + n0 + 4 * c);
            e2v[bi][c] = *(const v4f*)(E2 + (size_t)(b0 + bi) * K_ + n0 + 4 * c);
        }
    w3v[0] = *(const v4f*)(W3 + n0);
    w3v[1] = *(const v4f*)(W3 + n0 + 4);
    const float b3v = b3[0];

    v4f fb[2][4];
#pragma unroll
    for (int c = 0; c < 2; c++) {
        fb[0][c]     = *(const v4f*)(F1 + (size_t)kw * K_ + n0 + 4 * c);
        fb[0][2 + c] = *(const v4f*)(F2 + (size_t)kw * K_ + n0 + 4 * c);
    }

    const bool h32 = (l & 32), h16 = (l & 16), h8 = (l & 8), h4 = (l & 4), h2 = (l & 2);
    const int my_kk = (l >> 3) & 7, my_bi = (l >> 1) & 3;
    float gsum = 0.f;

#pragma unroll
    for (int r = 0; r < 2; r++) {
        float acc[32];
#pragma unroll
        for (int i = 0; i < 32; i++) acc[i] = 0.f;
#pragma unroll
        for (int kk = 0; kk < 8; kk++) {
            const int cur = kk & 1, nxt = cur ^ 1;
            const int k = kw + r * 8 + kk;
            if (r < 1 || kk < 7) {
#pragma unroll
                for (int c = 0; c < 2; c++) {
                    fb[nxt][c]     = *(const v4f*)(F1 + (size_t)(k + 1) * K_ + n0 + 4 * c);
                    fb[nxt][2 + c] = *(const v4f*)(F2 + (size_t)(k + 1) * K_ + n0 + 4 * c);
                }
            }
            v4f tacc[4];
#pragma unroll
            for (int bi = 0; bi < 4; bi++) { tacc[bi] = (v4f){0.f, 0.f, 0.f, 0.f}; }
#pragma unroll
            for (int c = 0; c < 2; c++) {
                const v4f f1c = fb[cur][c];
                const v4f f2c = fb[cur][2 + c];
#pragma unroll
                for (int bi = 0; bi < 4; bi++) {
                    const v4f pd = e1v[bi][c] * f1c + 1.0f;
                    const v4f qd = e2v[bi][c] * f2c + 1.0f;
                    const v4f den = pd * qd;
                    v4f rc;
                    rc.x = frcp(den.x); rc.y = frcp(den.y);
                    rc.z = frcp(den.z); rc.w = frcp(den.w);
                    const v4f wn = (qd - pd) * w3v[c];
                    tacc[bi] += wn * rc;
                }
            }
#pragma unroll
            for (int bi = 0; bi < 4; bi++)
                acc[kk * 4 + bi] = (tacc[bi].x + tacc[bi].y) + (tacc[bi].z + tacc[bi].w);
        }
        // butterfly transpose-reduce: 32 values over 64 lanes
#pragma unroll
        for (int i = 0; i < 16; i++) {
            const float lo = acc[i], hi = acc[i + 16];
            const float mine = h32 ? hi : lo, send = h32 ? lo : hi;
            acc[i] = mine + __shfl_xor(send, 32, 64);
        }
#pragma unroll
        for (int i = 0; i < 8; i++) {
            const float lo = acc[i], hi = acc[i + 8];
            const float mine = h16 ? hi : lo, send = h16 ? lo : hi;
            acc[i] = mine + __shfl_xor(send, 16, 64);
        }
#pragma unroll
        for (int i = 0; i < 4; i++) {
            const float lo = acc[i], hi = acc[i + 4];
            const float mine = h8 ? hi : lo, send = h8 ? lo : hi;
            acc[i] = mine + __shfl_xor(send, 8, 64);
        }
#pragma unroll
        for (int i = 0; i < 2; i++) {
            const float lo = acc[i], hi = acc[i + 2];
            const float mine = h4 ? hi : lo, send = h4 ? lo : hi;
            acc[i] = mine + __shfl_xor(send, 4, 64);
        }
        {
            const float lo = acc[0], hi = acc[1];
            const float mine = h2 ? hi : lo, send = h2 ? lo : hi;
            acc[0] = mine + __shfl_xor(send, 2, 64);
        }
        acc[0] += __shfl_xor(acc[0], 1, 64);
        const float o = fsig(acc[0] + b3v);
        const int k_lane = kw + r * 8 + my_kk;
        gsum = fmaf(o, kn_emb[(size_t)(b0 + my_bi) * K_ + k_lane], gsum);
    }

    if (!(l & 1)) red[w][l >> 1] = gsum;
    __syncthreads();
    if (w == 0) {
        float v = red[0][l & 31] + red[1][l & 31] + red[2][l & 31] + red[3][l & 31];
        v += __shfl_xor(v, 4, 64);
        v += __shfl_xor(v, 8, 64);
        v += __shfl_xor(v, 16, 64);
        if (l < 4)
            __hip_atomic_store(&partial[(size_t)(b0 + l) * 8 + blockIdx.x], v,
                               __ATOMIC_RELEASE, __HIP_MEMORY_SCOPE_AGENT);
    }
    __syncthreads();
    if (t == 0) {
        const unsigned old = __hip_atomic_fetch_add(&cnt[blockIdx.y], 1u,
                             __ATOMIC_ACQ_REL, __HIP_MEMORY_SCOPE_AGENT);
        sdone = (old == 7u) ? 1 : 0;
    }
    __syncthreads();
    if (sdone) {
        const int bi2 = w, ll = l;
        float den = 0.f;
#pragma unroll
        for (int c2 = 0; c2 < 8; c2++)
            den += kn_emb[(size_t)(b0 + bi2) * K_ + c2 * 64 + ll];
#pragma unroll
        for (int off = 32; off; off >>= 1) den += __shfl_xor(den, off, 64);
        if (ll == 0) {
            float num = 0.f;
#pragma unroll
            for (int kg = 0; kg < 8; kg++)
                num += __hip_atomic_load(&partial[(size_t)(b0 + bi2) * 8 + kg],
                                         __ATOMIC_ACQUIRE, __HIP_MEMORY_SCOPE_AGENT);
            out[b0 + bi2] = num / den;
        }
    }
}

extern "C" void kernel_launch(void* const* d_in, const int* in_sizes, int n_in,
                              void* d_out, int out_size, void* d_ws, size_t ws_size,
                              hipStream_t stream) {
    const int*   stu_id     = (const int*)d_in[0];
    const int*   exer_id    = (const int*)d_in[1];
    const float* kn_emb     = (const float*)d_in[2];
    const float* stu_table  = (const float*)d_in[3];
    const float* exer_table = (const float*)d_in[4];
    const float* kn_table   = (const float*)d_in[5];
    const float* W1         = (const float*)d_in[6];
    const float* W2         = (const float*)d_in[7];
    const float* W3         = (const float*)d_in[8];
    const float* b3         = (const float*)d_in[9];
    float* out = (float*)d_out;

    float* ws = (float*)d_ws;
    float* F1       = ws;                                    // K*K
    float* F2       = F1 + (size_t)K_ * K_;                  // K*K
    float* E        = F2 + (size_t)K_ * K_;                  // 2 * B*K
    ushort* Sbu     = (ushort*)(E + 2 * (size_t)B_ * K_);    // 2 * B*K ushorts
    float* partial  = (float*)(Sbu + 2 * (size_t)B_ * K_);   // B*8
    unsigned* cnt   = (unsigned*)(partial + (size_t)B_ * 8); // 64

    kPrep<<<192, 256, 0, stream>>>(stu_id, exer_id, stu_table, exer_table,
                                   kn_table, W1, W2, Sbu, F1, F2, cnt);
    kE<<<128, 256, 0, stream>>>(Sbu, W1, W2, E);
    kMain<<<dim3(8, 64), 256, 0, stream>>>(F1, F2, E, W3, b3, kn_emb,
                                           partial, cnt, out);
}

// Round 5
// 85.136 us; speedup vs baseline: 1.0247x; 1.0247x over previous
//
#include <hip/hip_runtime.h>

#define B_ 256
#define K_ 512
#define D_ 64
#define KD_ 576
#define NB 8          // b per block in kMain
#define NSP 16        // n splits
#define NCH 32        // n per chunk = K_/NSP
#define LOG2E 1.44269504088896340736f

typedef float v2f __attribute__((ext_vector_type(2)));
typedef float v4f __attribute__((ext_vector_type(4)));
typedef short bf16x8 __attribute__((ext_vector_type(8)));
typedef float f32x16 __attribute__((ext_vector_type(16)));

#define ZERO16 {0.f,0.f,0.f,0.f,0.f,0.f,0.f,0.f,0.f,0.f,0.f,0.f,0.f,0.f,0.f,0.f}

__device__ __forceinline__ float fexp2(float x) {
#if __has_builtin(__builtin_amdgcn_exp2f)
    return __builtin_amdgcn_exp2f(x);
#else
    float r; asm("v_exp_f32 %0, %1" : "=v"(r) : "v"(x)); return r;
#endif
}
__device__ __forceinline__ float frcp(float x) {
#if __has_builtin(__builtin_amdgcn_rcpf)
    return __builtin_amdgcn_rcpf(x);
#else
    float r; asm("v_rcp_f32 %0, %1" : "=v"(r) : "v"(x)); return r;
#endif
}
__device__ __forceinline__ float fsig(float x) {
    return frcp(1.0f + fexp2(-LOG2E * x));
}
__device__ __forceinline__ ushort f2bf(float f) {
    union { float f; unsigned u; } v; v.f = f;
    return (ushort)((v.u + 0x7FFFu + ((v.u >> 16) & 1u)) >> 16);
}
__device__ __forceinline__ bf16x8 ldcvt8(const float* p) {
    float4 a = *(const float4*)p;
    float4 b = *(const float4*)(p + 4);
    bf16x8 r;
    r[0] = (short)f2bf(a.x); r[1] = (short)f2bf(a.y);
    r[2] = (short)f2bf(a.z); r[3] = (short)f2bf(a.w);
    r[4] = (short)f2bf(b.x); r[5] = (short)f2bf(b.y);
    r[6] = (short)f2bf(b.z); r[7] = (short)f2bf(b.w);
    return r;
}

// ---------------------------------------------------------------------------
// kPrep (192 blocks x 256 thr):
//  [0,64):   Sb[tab][b][n] = bf16(sigmoid(table_row[b] . kn[n]))      MFMA
//  [64,192): FT[mat][n][k] = exp(-(kn[k] . W[n, K:K+D]))  fp32 TRANSPOSED
//            (LDS-transposed so kMain gets k-contiguous rows)
//  block 0 zeroes finisher counters.
// ---------------------------------------------------------------------------
__global__ void __launch_bounds__(256) kPrep(const int* __restrict__ sid,
                                             const int* __restrict__ eid,
                                             const float* __restrict__ stu_t,
                                             const float* __restrict__ exer_t,
                                             const float* __restrict__ kn_t,
                                             const float* __restrict__ W1,
                                             const float* __restrict__ W2,
                                             ushort* __restrict__ Sbu,
                                             float* __restrict__ FT1,
                                             float* __restrict__ FT2,
                                             unsigned* __restrict__ cnt) {
    __shared__ float fts[64][65];
    const int bid = blockIdx.x, t = threadIdx.x;
    const int l = t & 63, w = t >> 6;
    const int dk = (l >> 5) * 8;
    if (bid == 0 && t < 64) cnt[t] = 0u;
    if (bid < 64) {
        const int tab = bid >> 5, bt = (bid >> 3) & 3, nt = bid & 7;
        const int b0 = bt * 64, n0 = nt * 64;
        const int brow = b0 + (w & 1) * 32 + (l & 31);
        const int ncol = n0 + (w >> 1) * 32 + (l & 31);
        const int id = (tab ? eid : sid)[brow];
        const float* ar = (tab ? exer_t : stu_t) + (size_t)id * D_;
        const float* br = kn_t + (size_t)ncol * D_;
        f32x16 acc = ZERO16;
#pragma unroll
        for (int kk = 0; kk < 4; kk++) {
            bf16x8 a = ldcvt8(ar + kk * 16 + dk);
            bf16x8 b = ldcvt8(br + kk * 16 + dk);
            acc = __builtin_amdgcn_mfma_f32_32x32x16_bf16(a, b, acc, 0, 0, 0);
        }
        ushort* So = Sbu + (size_t)tab * B_ * K_;
#pragma unroll
        for (int r = 0; r < 16; r++) {
            const int row = (r & 3) + 8 * (r >> 2) + 4 * (l >> 5);
            So[(size_t)(b0 + (w & 1) * 32 + row) * K_ + ncol] = f2bf(fsig(acc[r]));
        }
    } else {
        const int fid = bid - 64;
        const int mat = fid >> 6, kt = (fid >> 3) & 7, nt = fid & 7;
        const int k0 = kt * 64, n0 = nt * 64;
        const int krow = k0 + (w & 1) * 32 + (l & 31);
        const int ncol = n0 + (w >> 1) * 32 + (l & 31);
        const float* Wm = mat ? W2 : W1;
        const float* ar = kn_t + (size_t)krow * D_;
        const float* br = Wm + (size_t)ncol * KD_ + K_;
        f32x16 acc = ZERO16;
#pragma unroll
        for (int kk = 0; kk < 4; kk++) {
            bf16x8 a = ldcvt8(ar + kk * 16 + dk);
            bf16x8 b = ldcvt8(br + kk * 16 + dk);
            acc = __builtin_amdgcn_mfma_f32_32x32x16_bf16(a, b, acc, 0, 0, 0);
        }
        // transpose in LDS: fts[n_local][k_local]
        const int nl_ = (w >> 1) * 32 + (l & 31);
#pragma unroll
        for (int r = 0; r < 16; r++) {
            const int row = (r & 3) + 8 * (r >> 2) + 4 * (l >> 5);
            fts[nl_][(w & 1) * 32 + row] = fexp2(-LOG2E * acc[r]);
        }
        __syncthreads();
        float* Fo = mat ? FT2 : FT1;
#pragma unroll
        for (int i = 0; i < 16; i++) {
            const int q = i * 256 + t;
            const int r_ = q >> 6, c_ = q & 63;
            Fo[(size_t)(n0 + r_) * K_ + k0 + c_] = fts[r_][c_];
        }
    }
}

// ---------------------------------------------------------------------------
// kE (128 blocks x 256 thr): E[mat][b][n] = exp(-(S[b,:] . W[n,0:K]))
// Full K=512 contraction; 4 waves = (n-quad 2) x (k-half 2); halves combined
// in LDS; exp fused on store.
// ---------------------------------------------------------------------------
__global__ void __launch_bounds__(256) kE(const ushort* __restrict__ Sbu,
                                          const float* __restrict__ W1,
                                          const float* __restrict__ W2,
                                          float* __restrict__ E) {
    __shared__ float lacc[4][32][33];
    const int bid = blockIdx.x, t = threadIdx.x;
    const int nt = bid & 7, bt = (bid >> 3) & 7, mat = bid >> 6;
    const int l = t & 63, w = t >> 6;
    const int q = w & 1, h = w >> 1;
    const int m0 = nt * 64, b0 = bt * 32;
    const int arow = b0 + (l & 31);
    const int brow = m0 + q * 32 + (l & 31);
    const float* W = mat ? W2 : W1;
    const short* Sp = (const short*)Sbu + (size_t)(mat * B_ + arow) * K_
                      + h * 256 + (l >> 5) * 8;
    const float* Wp = W + (size_t)brow * KD_ + h * 256 + (l >> 5) * 8;
    f32x16 acc = ZERO16;
#pragma unroll
    for (int kk = 0; kk < 16; kk++) {
        bf16x8 a = *(const bf16x8*)(Sp + kk * 16);
        bf16x8 b = ldcvt8(Wp + kk * 16);
        acc = __builtin_amdgcn_mfma_f32_32x32x16_bf16(a, b, acc, 0, 0, 0);
    }
#pragma unroll
    for (int r = 0; r < 16; r++) {
        const int row = (r & 3) + 8 * (r >> 2) + 4 * (l >> 5);
        lacc[h * 2 + q][row][l & 31] = acc[r];
    }
    __syncthreads();
#pragma unroll
    for (int i = 0; i < 8; i++) {
        const int o = t + i * 256;
        const int q2 = o >> 10, row = (o >> 5) & 31, col = o & 31;
        const float v = lacc[q2][row][col] + lacc[2 + q2][row][col];
        E[(size_t)mat * B_ * K_ + (size_t)(b0 + row) * K_ + m0 + q2 * 32 + col]
            = fexp2(-LOG2E * v);
    }
}

// ---------------------------------------------------------------------------
// kMain: grid (NSP=16 n-chunks, 32 bgroups), 256 thr (4 waves).
// Lane owns 2 k's (v2f); wave owns 128 k; block = 8 b x 512 k x 32 n.
// e/w3 via uniform LDS broadcast; FT rows coalesced per-lane; acc in regs,
// NO cross-lane ops in hot loop. Partials T[nc][b][k]; fused finisher.
// ---------------------------------------------------------------------------
__global__ void __launch_bounds__(256, 2) kMain(const float* __restrict__ FT1,
                                                const float* __restrict__ FT2,
                                                const float* __restrict__ Ebase,
                                                const float* __restrict__ W3,
                                                const float* __restrict__ b3,
                                                const float* __restrict__ kn_emb,
                                                float* __restrict__ T,
                                                unsigned* __restrict__ cnt,
                                                float* __restrict__ out) {
    __shared__ float eis[2][NCH][NB];
    __shared__ float w3s[NCH];
    __shared__ float redn[4][NB], redd[4][NB];
    __shared__ int sdone;
    const int t = threadIdx.x;
    const int l = t & 63, w = t >> 6;
    const int nc = blockIdx.x;
    const int bg = blockIdx.y;
    const int b0 = bg * NB;
    const int n0 = nc * NCH;
    const float* E1 = Ebase;
    const float* E2 = Ebase + (size_t)B_ * K_;

    // prologue: e-broadcast table + w3
    for (int idx = t; idx < 2 * NCH * NB; idx += 256) {
        const int mat = idx >> 8, nl = (idx >> 3) & 31, b = idx & 7;
        const float* Em = mat ? E2 : E1;
        eis[mat][nl][b] = Em[(size_t)(b0 + b) * K_ + n0 + nl];
    }
    if (t < NCH) w3s[t] = W3[n0 + t];
    __syncthreads();

    const int koff = w * 128 + 2 * l;
    const float* f1p = FT1 + (size_t)n0 * K_ + koff;
    const float* f2p = FT2 + (size_t)n0 * K_ + koff;

    v2f acc[NB];
#pragma unroll
    for (int b = 0; b < NB; b++) acc[b] = (v2f){0.f, 0.f};

    v2f f1c = *(const v2f*)f1p;
    v2f f2c = *(const v2f*)f2p;
#pragma unroll 4
    for (int nl = 0; nl < NCH; nl++) {
        // unconditional prefetch (over-read lands in adjacent ws buffers: safe)
        const v2f f1n = *(const v2f*)(f1p + (size_t)(nl + 1) * K_);
        const v2f f2n = *(const v2f*)(f2p + (size_t)(nl + 1) * K_);
        const float w3n = w3s[nl];
        const v4f e1a = *(const v4f*)&eis[0][nl][0];
        const v4f e1b = *(const v4f*)&eis[0][nl][4];
        const v4f e2a = *(const v4f*)&eis[1][nl][0];
        const v4f e2b = *(const v4f*)&eis[1][nl][4];
#pragma unroll
        for (int b = 0; b < NB; b++) {
            const float e1 = (b < 4) ? e1a[b & 3] : e1b[b & 3];
            const float e2 = (b < 4) ? e2a[b & 3] : e2b[b & 3];
            const v2f pd = e1 * f1c + 1.0f;
            const v2f qd = e2 * f2c + 1.0f;
            const v2f den = pd * qd;
            v2f rc; rc.x = frcp(den.x); rc.y = frcp(den.y);
            const v2f tt = (qd - pd) * w3n;
            acc[b] += tt * rc;
        }
        f1c = f1n; f2c = f2n;
    }

#pragma unroll
    for (int b = 0; b < NB; b++)
        *(v2f*)(T + ((size_t)nc * B_ + b0 + b) * K_ + koff) = acc[b];

    __syncthreads();   // compiler drains vmcnt before barrier -> stores done
    if (t == 0) {
        __threadfence();
        const unsigned old = __hip_atomic_fetch_add(&cnt[bg], 1u,
                             __ATOMIC_ACQ_REL, __HIP_MEMORY_SCOPE_AGENT);
        sdone = (old == NSP - 1) ? 1 : 0;
    }
    __syncthreads();
    if (!sdone) return;
    __threadfence();

    // finisher: sum 16 n-partials -> sigmoid -> weighted sum / count
    const float b3v = b3[0];
    const int kk2 = 2 * t;       // k, k+1
    float np[NB], dp[NB];
#pragma unroll
    for (int b = 0; b < NB; b++) {
        v2f s = {0.f, 0.f};
#pragma unroll
        for (int c = 0; c < NSP; c++)
            s += *(const v2f*)(T + ((size_t)c * B_ + b0 + b) * K_ + kk2);
        const v2f ke = *(const v2f*)(kn_emb + (size_t)(b0 + b) * K_ + kk2);
        np[b] = fsig(s.x + b3v) * ke.x + fsig(s.y + b3v) * ke.y;
        dp[b] = ke.x + ke.y;
    }
#pragma unroll
    for (int b = 0; b < NB; b++) {
#pragma unroll
        for (int off = 32; off; off >>= 1) {
            np[b] += __shfl_xor(np[b], off, 64);
            dp[b] += __shfl_xor(dp[b], off, 64);
        }
    }
    if (l == 0) {
#pragma unroll
        for (int b = 0; b < NB; b++) { redn[w][b] = np[b]; redd[w][b] = dp[b]; }
    }
    __syncthreads();
    if (t < NB) {
        const float num = redn[0][t] + redn[1][t] + redn[2][t] + redn[3][t];
        const float den = redd[0][t] + redd[1][t] + redd[2][t] + redd[3][t];
        out[b0 + t] = num / den;
    }
}

extern "C" void kernel_launch(void* const* d_in, const int* in_sizes, int n_in,
                              void* d_out, int out_size, void* d_ws, size_t ws_size,
                              hipStream_t stream) {
    const int*   stu_id     = (const int*)d_in[0];
    const int*   exer_id    = (const int*)d_in[1];
    const float* kn_emb     = (const float*)d_in[2];
    const float* stu_table  = (const float*)d_in[3];
    const float* exer_table = (const float*)d_in[4];
    const float* kn_table   = (const float*)d_in[5];
    const float* W1         = (const float*)d_in[6];
    const float* W2         = (const float*)d_in[7];
    const float* W3         = (const float*)d_in[8];
    const float* b3         = (const float*)d_in[9];
    float* out = (float*)d_out;

    float* ws = (float*)d_ws;
    float* FT1      = ws;                                    // K*K
    float* FT2      = FT1 + (size_t)K_ * K_;                 // K*K
    float* E        = FT2 + (size_t)K_ * K_;                 // 2*B*K  (right after FT2: over-read target)
    ushort* Sbu     = (ushort*)(E + 2 * (size_t)B_ * K_);    // 2*B*K ushorts
    float* T        = (float*)(Sbu + 2 * (size_t)B_ * K_);   // NSP*B*K
    unsigned* cnt   = (unsigned*)(T + (size_t)NSP * B_ * K_); // 64

    kPrep<<<192, 256, 0, stream>>>(stu_id, exer_id, stu_table, exer_table,
                                   kn_table, W1, W2, Sbu, FT1, FT2, cnt);
    kE<<<128, 256, 0, stream>>>(Sbu, W1, W2, E);
    kMain<<<dim3(NSP, B_ / NB), 256, 0, stream>>>(FT1, FT2, E, W3, b3, kn_emb,
                                                  T, cnt, out);
}

// Round 6
// 39.581 us; speedup vs baseline: 2.2041x; 2.1509x over previous
//
#include <hip/hip_runtime.h>

#define B_ 256
#define K_ 512
#define D_ 64
#define KD_ 576
#define LOG2E 1.44269504088896340736f

typedef float v2f __attribute__((ext_vector_type(2)));
typedef float v4f __attribute__((ext_vector_type(4)));
typedef short bf16x8 __attribute__((ext_vector_type(8)));
typedef float f32x16 __attribute__((ext_vector_type(16)));

#define ZERO16 {0.f,0.f,0.f,0.f,0.f,0.f,0.f,0.f,0.f,0.f,0.f,0.f,0.f,0.f,0.f,0.f}

__device__ __forceinline__ float fexp2(float x) {
#if __has_builtin(__builtin_amdgcn_exp2f)
    return __builtin_amdgcn_exp2f(x);
#else
    float r; asm("v_exp_f32 %0, %1" : "=v"(r) : "v"(x)); return r;
#endif
}
__device__ __forceinline__ float frcp(float x) {
#if __has_builtin(__builtin_amdgcn_rcpf)
    return __builtin_amdgcn_rcpf(x);
#else
    float r; asm("v_rcp_f32 %0, %1" : "=v"(r) : "v"(x)); return r;
#endif
}
__device__ __forceinline__ float fsig(float x) {
    return frcp(1.0f + fexp2(-LOG2E * x));
}
__device__ __forceinline__ ushort f2bf(float f) {
    union { float f; unsigned u; } v; v.f = f;
    return (ushort)((v.u + 0x7FFFu + ((v.u >> 16) & 1u)) >> 16);
}
__device__ __forceinline__ bf16x8 ldcvt8(const float* p) {
    float4 a = *(const float4*)p;
    float4 b = *(const float4*)(p + 4);
    bf16x8 r;
    r[0] = (short)f2bf(a.x); r[1] = (short)f2bf(a.y);
    r[2] = (short)f2bf(a.z); r[3] = (short)f2bf(a.w);
    r[4] = (short)f2bf(b.x); r[5] = (short)f2bf(b.y);
    r[6] = (short)f2bf(b.z); r[7] = (short)f2bf(b.w);
    return r;
}

// ---------------------------------------------------------------------------
// kPrep (192 blocks x 256 thr):
//  [0,64):   Sb[tab][b][n] = bf16(sigmoid(table_row[b] . kn[n]))      MFMA
//  [64,192): FT[mat][n][k] = exp(-(kn[k] . W[n, K:K+D]))  fp32 TRANSPOSED
// ---------------------------------------------------------------------------
__global__ void __launch_bounds__(256) kPrep(const int* __restrict__ sid,
                                             const int* __restrict__ eid,
                                             const float* __restrict__ stu_t,
                                             const float* __restrict__ exer_t,
                                             const float* __restrict__ kn_t,
                                             const float* __restrict__ W1,
                                             const float* __restrict__ W2,
                                             ushort* __restrict__ Sbu,
                                             float* __restrict__ FT1,
                                             float* __restrict__ FT2) {
    __shared__ float fts[64][65];
    const int bid = blockIdx.x, t = threadIdx.x;
    const int l = t & 63, w = t >> 6;
    const int dk = (l >> 5) * 8;
    if (bid < 64) {
        const int tab = bid >> 5, bt = (bid >> 3) & 3, nt = bid & 7;
        const int b0 = bt * 64, n0 = nt * 64;
        const int brow = b0 + (w & 1) * 32 + (l & 31);
        const int ncol = n0 + (w >> 1) * 32 + (l & 31);
        const int id = (tab ? eid : sid)[brow];
        const float* ar = (tab ? exer_t : stu_t) + (size_t)id * D_;
        const float* br = kn_t + (size_t)ncol * D_;
        f32x16 acc = ZERO16;
#pragma unroll
        for (int kk = 0; kk < 4; kk++) {
            bf16x8 a = ldcvt8(ar + kk * 16 + dk);
            bf16x8 b = ldcvt8(br + kk * 16 + dk);
            acc = __builtin_amdgcn_mfma_f32_32x32x16_bf16(a, b, acc, 0, 0, 0);
        }
        ushort* So = Sbu + (size_t)tab * B_ * K_;
#pragma unroll
        for (int r = 0; r < 16; r++) {
            const int row = (r & 3) + 8 * (r >> 2) + 4 * (l >> 5);
            So[(size_t)(b0 + (w & 1) * 32 + row) * K_ + ncol] = f2bf(fsig(acc[r]));
        }
    } else {
        const int fid = bid - 64;
        const int mat = fid >> 6, kt = (fid >> 3) & 7, nt = fid & 7;
        const int k0 = kt * 64, n0 = nt * 64;
        const int krow = k0 + (w & 1) * 32 + (l & 31);
        const int ncol = n0 + (w >> 1) * 32 + (l & 31);
        const float* Wm = mat ? W2 : W1;
        const float* ar = kn_t + (size_t)krow * D_;
        const float* br = Wm + (size_t)ncol * KD_ + K_;
        f32x16 acc = ZERO16;
#pragma unroll
        for (int kk = 0; kk < 4; kk++) {
            bf16x8 a = ldcvt8(ar + kk * 16 + dk);
            bf16x8 b = ldcvt8(br + kk * 16 + dk);
            acc = __builtin_amdgcn_mfma_f32_32x32x16_bf16(a, b, acc, 0, 0, 0);
        }
        // transpose in LDS: fts[n_local][k_local]
        const int nl_ = (w >> 1) * 32 + (l & 31);
#pragma unroll
        for (int r = 0; r < 16; r++) {
            const int row = (r & 3) + 8 * (r >> 2) + 4 * (l >> 5);
            fts[nl_][(w & 1) * 32 + row] = fexp2(-LOG2E * acc[r]);
        }
        __syncthreads();
        float* Fo = mat ? FT2 : FT1;
#pragma unroll
        for (int i = 0; i < 16; i++) {
            const int q = i * 256 + t;
            const int r_ = q >> 6, c_ = q & 63;
            Fo[(size_t)(n0 + r_) * K_ + k0 + c_] = fts[r_][c_];
        }
    }
}

// ---------------------------------------------------------------------------
// kE (128 blocks x 256 thr): E[mat][b][n] = exp(-(S[b,:] . W[n,0:K]))
// Full K=512 contraction; 4 waves = (n-quad 2) x (k-half 2); halves combined
// in LDS; exp fused on store.
// ---------------------------------------------------------------------------
__global__ void __launch_bounds__(256) kE(const ushort* __restrict__ Sbu,
                                          const float* __restrict__ W1,
                                          const float* __restrict__ W2,
                                          float* __restrict__ E) {
    __shared__ float lacc[4][32][33];
    const int bid = blockIdx.x, t = threadIdx.x;
    const int nt = bid & 7, bt = (bid >> 3) & 7, mat = bid >> 6;
    const int l = t & 63, w = t >> 6;
    const int q = w & 1, h = w >> 1;
    const int m0 = nt * 64, b0 = bt * 32;
    const int arow = b0 + (l & 31);
    const int brow = m0 + q * 32 + (l & 31);
    const float* W = mat ? W2 : W1;
    const short* Sp = (const short*)Sbu + (size_t)(mat * B_ + arow) * K_
                      + h * 256 + (l >> 5) * 8;
    const float* Wp = W + (size_t)brow * KD_ + h * 256 + (l >> 5) * 8;
    f32x16 acc = ZERO16;
#pragma unroll
    for (int kk = 0; kk < 16; kk++) {
        bf16x8 a = *(const bf16x8*)(Sp + kk * 16);
        bf16x8 b = ldcvt8(Wp + kk * 16);
        acc = __builtin_amdgcn_mfma_f32_32x32x16_bf16(a, b, acc, 0, 0, 0);
    }
#pragma unroll
    for (int r = 0; r < 16; r++) {
        const int row = (r & 3) + 8 * (r >> 2) + 4 * (l >> 5);
        lacc[h * 2 + q][row][l & 31] = acc[r];
    }
    __syncthreads();
#pragma unroll
    for (int i = 0; i < 8; i++) {
        const int o = t + i * 256;
        const int q2 = o >> 10, row = (o >> 5) & 31, col = o & 31;
        const float v = lacc[q2][row][col] + lacc[2 + q2][row][col];
        E[(size_t)mat * B_ * K_ + (size_t)(b0 + row) * K_ + m0 + q2 * 32 + col]
            = fexp2(-LOG2E * v);
    }
}

// ---------------------------------------------------------------------------
// kMain: grid (8 kg, 32 bg), 512 thr (8 waves). Lane owns k = kg*64+l;
// wave w handles n-slice [64w, 64w+64); 8 b per block.
// e-values: wave-uniform LDS broadcast (conflict-free); FT loads coalesced.
// Full n-sum combined in-block through LDS; o=sigmoid fused; per-(kg,b)
// weighted partial written. NO atomics, NO fences, NO T tensor.
// ---------------------------------------------------------------------------
__global__ void __launch_bounds__(512) kMain(const float* __restrict__ FT1,
                                             const float* __restrict__ FT2,
                                             const float* __restrict__ Ebase,
                                             const float* __restrict__ W3,
                                             const float* __restrict__ b3,
                                             const float* __restrict__ kn_emb,
                                             float* __restrict__ pO) {
    __shared__ float lds[8704];   // es: [mat][n][b] 8192 f; w3s: [512] f
    const int t = threadIdx.x;
    const int l = t & 63, w = t >> 6;
    const int kg = blockIdx.x, bg = blockIdx.y;
    const int b0 = bg * 8;
    const int k = kg * 64 + l;

    // es fill: lds[mat*4096 + n*8 + b] = E[mat][b0+b][n]; wave w -> 2 combos
#pragma unroll
    for (int c = 0; c < 2; c++) {
        const int combo = w * 2 + c;
        const int mat = combo >> 3, b = combo & 7;
        const float* src = Ebase + (size_t)mat * B_ * K_ + (size_t)(b0 + b) * K_;
#pragma unroll
        for (int j = 0; j < 8; j++) {
            const int n = j * 64 + l;
            lds[mat * 4096 + n * 8 + b] = src[n];
        }
    }
    lds[8192 + t] = W3[t];
    const float b3v = b3[0];
    __syncthreads();

    const int nbase = w * 64;
    const float* f1p = FT1 + (size_t)nbase * K_ + k;
    const float* f2p = FT2 + (size_t)nbase * K_ + k;

    v2f acc0 = {0.f, 0.f}, acc1 = {0.f, 0.f}, acc2 = {0.f, 0.f}, acc3 = {0.f, 0.f};

#pragma unroll 4
    for (int nl = 0; nl < 64; nl++) {
        const float f1 = f1p[(size_t)nl * K_];
        const float f2 = f2p[(size_t)nl * K_];
        const int n = nbase + nl;
        const float w3n = lds[8192 + n];
        const v4f e1a = *(const v4f*)&lds[n * 8];
        const v4f e1b = *(const v4f*)&lds[n * 8 + 4];
        const v4f e2a = *(const v4f*)&lds[4096 + n * 8];
        const v4f e2b = *(const v4f*)&lds[4096 + n * 8 + 4];
        {
            const v2f e1 = {e1a.x, e1a.y}, e2 = {e2a.x, e2a.y};
            const v2f pd = e1 * f1 + 1.0f, qd = e2 * f2 + 1.0f;
            const v2f den = pd * qd;
            v2f rc; rc.x = frcp(den.x); rc.y = frcp(den.y);
            acc0 += ((qd - pd) * w3n) * rc;
        }
        {
            const v2f e1 = {e1a.z, e1a.w}, e2 = {e2a.z, e2a.w};
            const v2f pd = e1 * f1 + 1.0f, qd = e2 * f2 + 1.0f;
            const v2f den = pd * qd;
            v2f rc; rc.x = frcp(den.x); rc.y = frcp(den.y);
            acc1 += ((qd - pd) * w3n) * rc;
        }
        {
            const v2f e1 = {e1b.x, e1b.y}, e2 = {e2b.x, e2b.y};
            const v2f pd = e1 * f1 + 1.0f, qd = e2 * f2 + 1.0f;
            const v2f den = pd * qd;
            v2f rc; rc.x = frcp(den.x); rc.y = frcp(den.y);
            acc2 += ((qd - pd) * w3n) * rc;
        }
        {
            const v2f e1 = {e1b.z, e1b.w}, e2 = {e2b.z, e2b.w};
            const v2f pd = e1 * f1 + 1.0f, qd = e2 * f2 + 1.0f;
            const v2f den = pd * qd;
            v2f rc; rc.x = frcp(den.x); rc.y = frcp(den.y);
            acc3 += ((qd - pd) * w3n) * rc;
        }
    }

    __syncthreads();   // all waves done reading es -> safe to overwrite
    {
        float* sa = lds + w * 512 + l * 8;   // sacc[w][k_l][b], first 4096 f
        *(v2f*)(sa + 0) = acc0;
        *(v2f*)(sa + 2) = acc1;
        *(v2f*)(sa + 4) = acc2;
        *(v2f*)(sa + 6) = acc3;
    }
    __syncthreads();
    // thread t: b = w, k_l = l  (wave b holds all 64 k of that b)
    float s = 0.f;
#pragma unroll
    for (int ww = 0; ww < 8; ww++) s += lds[ww * 512 + l * 8 + w];
    const float o = fsig(s + b3v);
    float g = o * kn_emb[(size_t)(b0 + w) * K_ + kg * 64 + l];
#pragma unroll
    for (int off = 32; off; off >>= 1) g += __shfl_xor(g, off, 64);
    if (l == 0) pO[bg * 64 + kg * 8 + w] = g;   // pO[bg][kg][b]
}

// ---------------------------------------------------------------------------
// kFin (32 blocks x 512 thr): wave w -> b = bg*8+w.
// out[b] = (sum_kg pO[bg][kg][b]) / (sum_n kn_emb[b][n])
// ---------------------------------------------------------------------------
__global__ void __launch_bounds__(512) kFin(const float* __restrict__ pO,
                                            const float* __restrict__ kn_emb,
                                            float* __restrict__ out) {
    const int t = threadIdx.x, l = t & 63, w = t >> 6;
    const int bg = blockIdx.x;
    const int b = bg * 8 + w;
    float den = 0.f;
#pragma unroll
    for (int c = 0; c < 8; c++) den += kn_emb[(size_t)b * K_ + c * 64 + l];
#pragma unroll
    for (int off = 32; off; off >>= 1) den += __shfl_xor(den, off, 64);
    float num = (l < 8) ? pO[bg * 64 + l * 8 + w] : 0.f;
    num += __shfl_xor(num, 1, 64);
    num += __shfl_xor(num, 2, 64);
    num += __shfl_xor(num, 4, 64);
    if (l == 0) out[b] = num / den;
}

extern "C" void kernel_launch(void* const* d_in, const int* in_sizes, int n_in,
                              void* d_out, int out_size, void* d_ws, size_t ws_size,
                              hipStream_t stream) {
    const int*   stu_id     = (const int*)d_in[0];
    const int*   exer_id    = (const int*)d_in[1];
    const float* kn_emb     = (const float*)d_in[2];
    const float* stu_table  = (const float*)d_in[3];
    const float* exer_table = (const float*)d_in[4];
    const float* kn_table   = (const float*)d_in[5];
    const float* W1         = (const float*)d_in[6];
    const float* W2         = (const float*)d_in[7];
    const float* W3         = (const float*)d_in[8];
    const float* b3         = (const float*)d_in[9];
    float* out = (float*)d_out;

    float* ws = (float*)d_ws;
    float* FT1      = ws;                                    // K*K
    float* FT2      = FT1 + (size_t)K_ * K_;                 // K*K
    float* E        = FT2 + (size_t)K_ * K_;                 // 2*B*K
    ushort* Sbu     = (ushort*)(E + 2 * (size_t)B_ * K_);    // 2*B*K ushorts
    float* pO       = (float*)(Sbu + 2 * (size_t)B_ * K_);   // 32*8*8 = 2048

    kPrep<<<192, 256, 0, stream>>>(stu_id, exer_id, stu_table, exer_table,
                                   kn_table, W1, W2, Sbu, FT1, FT2);
    kE<<<128, 256, 0, stream>>>(Sbu, W1, W2, E);
    kMain<<<dim3(8, 32), 512, 0, stream>>>(FT1, FT2, E, W3, b3, kn_emb, pO);
    kFin<<<32, 512, 0, stream>>>(pO, kn_emb, out);
}

// Round 7
// 36.522 us; speedup vs baseline: 2.3888x; 1.0838x over previous
//
#include <hip/hip_runtime.h>

#define B_ 256
#define K_ 512
#define D_ 64
#define KD_ 576
#define LOG2E 1.44269504088896340736f

typedef float v2f __attribute__((ext_vector_type(2)));
typedef float v4f __attribute__((ext_vector_type(4)));
typedef short bf16x8 __attribute__((ext_vector_type(8)));
typedef float f32x16 __attribute__((ext_vector_type(16)));

#define ZERO16 {0.f,0.f,0.f,0.f,0.f,0.f,0.f,0.f,0.f,0.f,0.f,0.f,0.f,0.f,0.f,0.f}

__device__ __forceinline__ float fexp2(float x) {
#if __has_builtin(__builtin_amdgcn_exp2f)
    return __builtin_amdgcn_exp2f(x);
#else
    float r; asm("v_exp_f32 %0, %1" : "=v"(r) : "v"(x)); return r;
#endif
}
__device__ __forceinline__ float frcp(float x) {
#if __has_builtin(__builtin_amdgcn_rcpf)
    return __builtin_amdgcn_rcpf(x);
#else
    float r; asm("v_rcp_f32 %0, %1" : "=v"(r) : "v"(x)); return r;
#endif
}
__device__ __forceinline__ float fsig(float x) {
    return frcp(1.0f + fexp2(-LOG2E * x));
}
__device__ __forceinline__ ushort f2bf(float f) {
    union { float f; unsigned u; } v; v.f = f;
    return (ushort)((v.u + 0x7FFFu + ((v.u >> 16) & 1u)) >> 16);
}
__device__ __forceinline__ bf16x8 ldcvt8(const float* p) {
    float4 a = *(const float4*)p;
    float4 b = *(const float4*)(p + 4);
    bf16x8 r;
    r[0] = (short)f2bf(a.x); r[1] = (short)f2bf(a.y);
    r[2] = (short)f2bf(a.z); r[3] = (short)f2bf(a.w);
    r[4] = (short)f2bf(b.x); r[5] = (short)f2bf(b.y);
    r[6] = (short)f2bf(b.z); r[7] = (short)f2bf(b.w);
    return r;
}

// ---------------------------------------------------------------------------
// kS (64 blocks x 256): Sb[tab][b][n] = bf16(sigmoid(table_row[b] . kn[n]))
// Short critical path: only this blocks kEF's E-part.
// ---------------------------------------------------------------------------
__global__ void __launch_bounds__(256) kS(const int* __restrict__ sid,
                                          const int* __restrict__ eid,
                                          const float* __restrict__ stu_t,
                                          const float* __restrict__ exer_t,
                                          const float* __restrict__ kn_t,
                                          ushort* __restrict__ Sbu) {
    const int bid = blockIdx.x, t = threadIdx.x;
    const int l = t & 63, w = t >> 6;
    const int dk = (l >> 5) * 8;
    const int tab = bid >> 5, bt = (bid >> 3) & 3, nt = bid & 7;
    const int b0 = bt * 64, n0 = nt * 64;
    const int brow = b0 + (w & 1) * 32 + (l & 31);
    const int ncol = n0 + (w >> 1) * 32 + (l & 31);
    const int id = (tab ? eid : sid)[brow];
    const float* ar = (tab ? exer_t : stu_t) + (size_t)id * D_;
    const float* br = kn_t + (size_t)ncol * D_;
    f32x16 acc = ZERO16;
#pragma unroll
    for (int kk = 0; kk < 4; kk++) {
        bf16x8 a = ldcvt8(ar + kk * 16 + dk);
        bf16x8 b = ldcvt8(br + kk * 16 + dk);
        acc = __builtin_amdgcn_mfma_f32_32x32x16_bf16(a, b, acc, 0, 0, 0);
    }
    ushort* So = Sbu + (size_t)tab * B_ * K_;
#pragma unroll
    for (int r = 0; r < 16; r++) {
        const int row = (r & 3) + 8 * (r >> 2) + 4 * (l >> 5);
        So[(size_t)(b0 + (w & 1) * 32 + row) * K_ + ncol] = f2bf(fsig(acc[r]));
    }
}

// ---------------------------------------------------------------------------
// kEF (384 blocks x 256):
//  [0,256):   E[mat][b][n] = exp(-(S[b,:] . W[n,0:K]))   32b x 32n tile,
//             4 waves = k-quarters (128 k each), combined in LDS.
//  [256,384): FT[mat][n][k] = exp(-(kn[k] . W[n,K:K+D])) transposed via LDS.
//             (independent of kS -> fills CUs while E waits on nothing else)
// ---------------------------------------------------------------------------
__global__ void __launch_bounds__(256) kEF(const ushort* __restrict__ Sbu,
                                           const float* __restrict__ W1,
                                           const float* __restrict__ W2,
                                           const float* __restrict__ kn_t,
                                           float* __restrict__ E,
                                           float* __restrict__ FT1,
                                           float* __restrict__ FT2) {
    __shared__ float shm[4224];
    const int bid = blockIdx.x, t = threadIdx.x;
    const int l = t & 63, w = t >> 6;
    if (bid < 256) {
        const int mat = bid >> 7, bt = (bid >> 4) & 7, nt = bid & 15;
        const int b0 = bt * 32, n0 = nt * 32;
        const int arow = b0 + (l & 31);
        const int nrow = n0 + (l & 31);
        const int koff = w * 128 + (l >> 5) * 8;
        const short* Sp = (const short*)Sbu + (size_t)(mat * B_ + arow) * K_ + koff;
        const float* Wp = (mat ? W2 : W1) + (size_t)nrow * KD_ + koff;
        f32x16 acc = ZERO16;
#pragma unroll
        for (int kk = 0; kk < 8; kk++) {
            bf16x8 a = *(const bf16x8*)(Sp + kk * 16);
            bf16x8 b = ldcvt8(Wp + kk * 16);
            acc = __builtin_amdgcn_mfma_f32_32x32x16_bf16(a, b, acc, 0, 0, 0);
        }
#pragma unroll
        for (int r = 0; r < 16; r++) {
            const int row = (r & 3) + 8 * (r >> 2) + 4 * (l >> 5);
            shm[w * 1056 + row * 33 + (l & 31)] = acc[r];
        }
        __syncthreads();
#pragma unroll
        for (int i = 0; i < 4; i++) {
            const int o = i * 256 + t;
            const int row = (o >> 5) & 31, col = o & 31;
            const float v = shm[row * 33 + col] + shm[1056 + row * 33 + col]
                          + shm[2112 + row * 33 + col] + shm[3168 + row * 33 + col];
            E[(size_t)mat * B_ * K_ + (size_t)(b0 + row) * K_ + n0 + col]
                = fexp2(-LOG2E * v);
        }
    } else {
        const int fid = bid - 256;
        const int mat = fid >> 6, kt = (fid >> 3) & 7, nt = fid & 7;
        const int k0 = kt * 64, n0 = nt * 64;
        const int krow = k0 + (w & 1) * 32 + (l & 31);
        const int ncol = n0 + (w >> 1) * 32 + (l & 31);
        const int dk = (l >> 5) * 8;
        const float* Wm = mat ? W2 : W1;
        const float* ar = kn_t + (size_t)krow * D_;
        const float* br = Wm + (size_t)ncol * KD_ + K_;
        f32x16 acc = ZERO16;
#pragma unroll
        for (int kk = 0; kk < 4; kk++) {
            bf16x8 a = ldcvt8(ar + kk * 16 + dk);
            bf16x8 b = ldcvt8(br + kk * 16 + dk);
            acc = __builtin_amdgcn_mfma_f32_32x32x16_bf16(a, b, acc, 0, 0, 0);
        }
        // transpose in LDS: shm[n_local*65 + k_local]
        const int nl_ = (w >> 1) * 32 + (l & 31);
#pragma unroll
        for (int r = 0; r < 16; r++) {
            const int row = (r & 3) + 8 * (r >> 2) + 4 * (l >> 5);
            shm[nl_ * 65 + (w & 1) * 32 + row] = fexp2(-LOG2E * acc[r]);
        }
        __syncthreads();
        float* Fo = mat ? FT2 : FT1;
#pragma unroll
        for (int i = 0; i < 16; i++) {
            const int q = i * 256 + t;
            const int r_ = q >> 6, c_ = q & 63;
            Fo[(size_t)(n0 + r_) * K_ + k0 + c_] = shm[r_ * 65 + c_];
        }
    }
}

// ---------------------------------------------------------------------------
// kMain: grid (8 kg, 32 bg, 2 ns), 512 thr (8 waves). Lane owns k = kg*64+l;
// wave w handles n-slice [ns*256 + 32w, +32); 8 b per block.
// e-values: wave-uniform LDS broadcast; FT loads coalesced 256B/wave.
// In-block n-half sum via LDS transpose; f32 partials out. NO atomics.
// ---------------------------------------------------------------------------
__global__ void __launch_bounds__(512) kMain(const float* __restrict__ FT1,
                                             const float* __restrict__ FT2,
                                             const float* __restrict__ Ebase,
                                             const float* __restrict__ W3,
                                             float* __restrict__ pPart) {
    __shared__ float lds[4352];   // es [mat][256n][8b] 16KB (reused as sacc) + w3 1KB
    const int t = threadIdx.x;
    const int l = t & 63, w = t >> 6;
    const int kg = blockIdx.x, bg = blockIdx.y, ns = blockIdx.z;
    const int b0 = bg * 8;
    const int k = kg * 64 + l;

    // es fill: lds[mat*2048 + nl*8 + b] = E[mat][b0+b][ns*256+nl]
#pragma unroll
    for (int c = 0; c < 2; c++) {
        const int combo = w * 2 + c;
        const int mat = combo >> 3, b = combo & 7;
        const float* src = Ebase + (size_t)mat * B_ * K_ + (size_t)(b0 + b) * K_
                         + ns * 256;
#pragma unroll
        for (int j = 0; j < 4; j++) {
            const int nl = j * 64 + l;
            lds[mat * 2048 + nl * 8 + b] = src[nl];
        }
    }
    if (t < 256) lds[4096 + t] = W3[ns * 256 + t];
    __syncthreads();

    const int nbase = w * 32;
    const float* f1p = FT1 + (size_t)(ns * 256 + nbase) * K_ + k;
    const float* f2p = FT2 + (size_t)(ns * 256 + nbase) * K_ + k;

    v2f acc0 = {0.f, 0.f}, acc1 = {0.f, 0.f}, acc2 = {0.f, 0.f}, acc3 = {0.f, 0.f};

#pragma unroll 4
    for (int nl = 0; nl < 32; nl++) {
        const float f1 = f1p[(size_t)nl * K_];
        const float f2 = f2p[(size_t)nl * K_];
        const int n = nbase + nl;
        const float w3n = lds[4096 + n];
        const v4f e1a = *(const v4f*)&lds[n * 8];
        const v4f e1b = *(const v4f*)&lds[n * 8 + 4];
        const v4f e2a = *(const v4f*)&lds[2048 + n * 8];
        const v4f e2b = *(const v4f*)&lds[2048 + n * 8 + 4];
        {
            const v2f e1 = {e1a.x, e1a.y}, e2 = {e2a.x, e2a.y};
            const v2f pd = e1 * f1 + 1.0f, qd = e2 * f2 + 1.0f;
            const v2f den = pd * qd;
            v2f rc; rc.x = frcp(den.x); rc.y = frcp(den.y);
            acc0 += ((qd - pd) * w3n) * rc;
        }
        {
            const v2f e1 = {e1a.z, e1a.w}, e2 = {e2a.z, e2a.w};
            const v2f pd = e1 * f1 + 1.0f, qd = e2 * f2 + 1.0f;
            const v2f den = pd * qd;
            v2f rc; rc.x = frcp(den.x); rc.y = frcp(den.y);
            acc1 += ((qd - pd) * w3n) * rc;
        }
        {
            const v2f e1 = {e1b.x, e1b.y}, e2 = {e2b.x, e2b.y};
            const v2f pd = e1 * f1 + 1.0f, qd = e2 * f2 + 1.0f;
            const v2f den = pd * qd;
            v2f rc; rc.x = frcp(den.x); rc.y = frcp(den.y);
            acc2 += ((qd - pd) * w3n) * rc;
        }
        {
            const v2f e1 = {e1b.z, e1b.w}, e2 = {e2b.z, e2b.w};
            const v2f pd = e1 * f1 + 1.0f, qd = e2 * f2 + 1.0f;
            const v2f den = pd * qd;
            v2f rc; rc.x = frcp(den.x); rc.y = frcp(den.y);
            acc3 += ((qd - pd) * w3n) * rc;
        }
    }

    __syncthreads();   // es reads done -> safe to overwrite
    {
        float* sa = lds + w * 512 + l * 8;   // sacc[w][k_l][b]
        *(v2f*)(sa + 0) = acc0;
        *(v2f*)(sa + 2) = acc1;
        *(v2f*)(sa + 4) = acc2;
        *(v2f*)(sa + 6) = acc3;
    }
    __syncthreads();
    // thread (w,l): b = w, k_l = l; sum the 8 wave n-slices
    float s = 0.f;
#pragma unroll
    for (int ww = 0; ww < 8; ww++) s += lds[ww * 512 + l * 8 + w];
    pPart[(((size_t)ns * 32 + bg) * 8 + w) * K_ + kg * 64 + l] = s;
}

// ---------------------------------------------------------------------------
// kFin (64 blocks x 256): wave w -> b = bid*4 + w.
// out[b] = sum_k sigmoid(part0+part1+b3) * kn_emb[b,k] / sum_n kn_emb[b,n]
// ---------------------------------------------------------------------------
__global__ void __launch_bounds__(256) kFin(const float* __restrict__ pPart,
                                            const float* __restrict__ kn_emb,
                                            const float* __restrict__ b3,
                                            float* __restrict__ out) {
    const int t = threadIdx.x, l = t & 63, w = t >> 6;
    const int b = blockIdx.x * 4 + w;
    const int bg = b >> 3, bi = b & 7;
    const float b3v = b3[0];
    const float* p0 = pPart + (((size_t)0 * 32 + bg) * 8 + bi) * K_;
    const float* p1 = pPart + (((size_t)1 * 32 + bg) * 8 + bi) * K_;
    const float* ke = kn_emb + (size_t)b * K_;
    float num = 0.f, den = 0.f;
#pragma unroll
    for (int c = 0; c < 8; c++) {
        const int kk = c * 64 + l;
        const float s = p0[kk] + p1[kk];
        const float kv = ke[kk];
        num = fmaf(fsig(s + b3v), kv, num);
        den += kv;
    }
#pragma unroll
    for (int off = 32; off; off >>= 1) {
        num += __shfl_xor(num, off, 64);
        den += __shfl_xor(den, off, 64);
    }
    if (l == 0) out[b] = num / den;
}

extern "C" void kernel_launch(void* const* d_in, const int* in_sizes, int n_in,
                              void* d_out, int out_size, void* d_ws, size_t ws_size,
                              hipStream_t stream) {
    const int*   stu_id     = (const int*)d_in[0];
    const int*   exer_id    = (const int*)d_in[1];
    const float* kn_emb     = (const float*)d_in[2];
    const float* stu_table  = (const float*)d_in[3];
    const float* exer_table = (const float*)d_in[4];
    const float* kn_table   = (const float*)d_in[5];
    const float* W1         = (const float*)d_in[6];
    const float* W2         = (const float*)d_in[7];
    const float* W3         = (const float*)d_in[8];
    const float* b3         = (const float*)d_in[9];
    float* out = (float*)d_out;

    float* ws = (float*)d_ws;
    float* FT1      = ws;                                    // K*K
    float* FT2      = FT1 + (size_t)K_ * K_;                 // K*K
    float* E        = FT2 + (size_t)K_ * K_;                 // 2*B*K
    ushort* Sbu     = (ushort*)(E + 2 * (size_t)B_ * K_);    // 2*B*K ushorts
    float* pPart    = (float*)(Sbu + 2 * (size_t)B_ * K_);   // 2*32*8*512 = 256K f

    kS<<<64, 256, 0, stream>>>(stu_id, exer_id, stu_table, exer_table,
                               kn_table, Sbu);
    kEF<<<384, 256, 0, stream>>>(Sbu, W1, W2, kn_table, E, FT1, FT2);
    kMain<<<dim3(8, 32, 2), 512, 0, stream>>>(FT1, FT2, E, W3, pPart);
    kFin<<<64, 256, 0, stream>>>(pPart, kn_emb, b3, out);
}